// Round 7
// baseline (502.567 us; speedup 1.0000x reference)
//
#include <hip/hip_runtime.h>
#include <hip/hip_bf16.h>

typedef unsigned short ushort_t;
typedef unsigned int uint_t;
typedef __attribute__((ext_vector_type(8))) short bf16x8;
typedef __attribute__((ext_vector_type(4))) float f32x4;

#define NB_T 512
#define NB_B 32
#define NB_M (NB_B * NB_T)     // 16384
#define KDIM 1536
#define MAXL 2048

__device__ __forceinline__ ushort_t f2bf(float f) {
  __hip_bfloat16 h = __float2bfloat16(f);
  return *reinterpret_cast<ushort_t*>(&h);
}
__device__ __forceinline__ float bf2f(ushort_t u) {
  __hip_bfloat16 h;
  *reinterpret_cast<ushort_t*>(&h) = u;
  return __bfloat162float(h);
}
__device__ __forceinline__ uint_t pack2(float a, float b) {
  return (uint_t)f2bf(a) | ((uint_t)f2bf(b) << 16);
}
__device__ __forceinline__ void gload_lds16(const void* g, void* l) {
  __builtin_amdgcn_global_load_lds((const __attribute__((address_space(1))) void*)g,
                                   (__attribute__((address_space(3))) void*)l, 16, 0, 0);
}

// ---------------- weight transpose (both convs in one dispatch):
// w[pk][i][o] f32 -> wt[p][o][kk*512+i] bf16
__global__ __launch_bounds__(256) void k_wt(const float* __restrict__ w1, const float* __restrict__ w2,
                                            ushort_t* __restrict__ wt1, ushort_t* __restrict__ wt2) {
  __shared__ float tile[64][65];
  int g = blockIdx.y;                 // 0..17
  const float* wsrc;
  ushort_t* wdst;
  if (g < 9) { wsrc = w1; wdst = wt1; } else { wsrc = w2; wdst = wt2; g -= 9; }
  const int p = g / 3, kk = g % 3;
  const int ot = (blockIdx.x & 7) * 64;
  const int it = (blockIdx.x >> 3) * 64;
  const int tx = threadIdx.x & 63;
  const int ty = threadIdx.x >> 6;
  const float* src = wsrc + (size_t)g * 512 * 512;
  #pragma unroll
  for (int r = ty; r < 64; r += 4)
    tile[r][tx] = src[(size_t)(it + r) * 512 + ot + tx];
  __syncthreads();
  #pragma unroll
  for (int r = ty; r < 64; r += 4)
    wdst[((size_t)(p * 512 + ot + r)) * KDIM + kk * 512 + it + tx] = f2bf(tile[tx][r]);
}

// ---------------- per-batch cumsum of masked duration + mel_len
__global__ __launch_bounds__(512) void k_cum(const int* __restrict__ dur, const unsigned char* __restrict__ mask,
                                             int* __restrict__ cum, float* __restrict__ mel_len_out) {
  __shared__ int s[512];
  const int b = blockIdx.x, t = threadIdx.x;
  int d = mask[b * NB_T + t] ? 0 : dur[b * NB_T + t];
  s[t] = d;
  __syncthreads();
  for (int off = 1; off < 512; off <<= 1) {
    int v = (t >= off) ? s[t - off] : 0;
    __syncthreads();
    s[t] += v;
    __syncthreads();
  }
  cum[b * NB_T + t] = s[t];
  if (t == 0) {
    int ml = s[511]; ml = ml < MAXL ? ml : MAXL;
    mel_len_out[b] = (float)ml;
  }
}

// ---------------- fused prep (+bucketize): xb_pad = bf(x), x2pad = bf(x + ptab[pi]),
//                  x3b = bf(x + ptab + etab), zero pad rows (xb/x2/lnp2)
__global__ __launch_bounds__(256) void k_prep(const float* __restrict__ x,
                                              const float* __restrict__ pt, const float* __restrict__ et,
                                              const float* __restrict__ pb, const float* __restrict__ eb,
                                              const float* __restrict__ ptab, const float* __restrict__ etab,
                                              ushort_t* __restrict__ xb_pad, ushort_t* __restrict__ x2pad,
                                              ushort_t* __restrict__ lnp2, ushort_t* __restrict__ x3b) {
  const int rp = blockIdx.x;               // 0..B*514-1
  const int b = rp / 514, j = rp % 514;
  const int tid = threadIdx.x;             // 2 elements each
  if (j == 0 || j == 513) {
    ((uint_t*)(xb_pad + (size_t)rp * 512))[tid] = 0u;
    ((uint_t*)(x2pad + (size_t)rp * 512))[tid] = 0u;
    ((uint_t*)(lnp2 + (size_t)rp * 512))[tid] = 0u;
    return;
  }
  const int m = b * NB_T + j - 1;
  float v = pt[m];
  int lo = 0, hi = 255;
  while (lo < hi) { int mid = (lo + hi) >> 1; if (pb[mid] < v) lo = mid + 1; else hi = mid; }
  const int pi = lo;
  v = et[m]; lo = 0; hi = 255;
  while (lo < hi) { int mid = (lo + hi) >> 1; if (eb[mid] < v) lo = mid + 1; else hi = mid; }
  const int ei = lo;

  const float2 xv = ((const float2*)(x + (size_t)m * 512))[tid];
  const float2 pv = ((const float2*)(ptab + (size_t)pi * 512))[tid];
  const float2 ev = ((const float2*)(etab + (size_t)ei * 512))[tid];
  ((uint_t*)(xb_pad + (size_t)rp * 512))[tid] = pack2(xv.x, xv.y);
  const float ax = xv.x + pv.x, ay = xv.y + pv.y;
  ((uint_t*)(x2pad + (size_t)rp * 512))[tid] = pack2(ax, ay);
  ((uint_t*)(x3b + (size_t)m * 512))[tid] = pack2(ax + ev.x, ay + ev.y);
}

// ---------------- 256x256 8-phase conv-as-GEMM (m201 template port)
// 512 thr, 8 waves (2Mx4N), BK=64, 24 K-tiles, dyn LDS 128 KiB (2 K-tile bufs),
// st_16x32 swizzle (linear LDS dest + inverse-swizzled global src + swizzled ds_read)
__global__ __launch_bounds__(512, 1) void k_gemm(const ushort_t* __restrict__ A0,
                                                 const ushort_t* __restrict__ A1,
                                                 const ushort_t* __restrict__ A2,
                                                 const ushort_t* __restrict__ Wt,
                                                 const float* __restrict__ bias,
                                                 ushort_t* __restrict__ H) {
  extern __shared__ char smem[];          // [2 bufs][A 32KB | B 32KB]
  const int tid = threadIdx.x;
  const int lane = tid & 63, wid = tid >> 6;
  const int wr = wid >> 2, wc = wid & 3;  // 2M x 4N wave grid
  const int l15 = lane & 15, l4 = lane >> 4;

  // bijective XCD-chunked swizzle: 384 blocks = 8 x 48
  const int bid = blockIdx.x;
  const int logical = (bid & 7) * 48 + (bid >> 3);
  const int pred = logical >> 7;          // 0..2
  const int tl = logical & 127;
  const int mt = tl >> 1, nt = tl & 1;
  const int m0 = mt << 8, n0 = nt << 8;
  const int b = m0 >> 9, t0 = m0 & 511;
  const long Arow0 = (long)b * 514 + t0 + 1;

  const ushort_t* Ap = (pred == 0) ? A0 : ((pred == 1) ? A1 : A2);
  const ushort_t* Wp = Wt + (size_t)pred * 512 * KDIM;
  const float* bp = bias + pred * 512;
  ushort_t* Hp = H + (size_t)pred * NB_M * 512;

  f32x4 acc[8][4];
  #pragma unroll
  for (int i = 0; i < 8; ++i)
    #pragma unroll
    for (int j = 0; j < 4; ++j) acc[i][j] = (f32x4)0.f;

  // stage one half-tile (16 KB): part 0=A-h0, 1=A-h1, 2=B-h0, 3=B-h1
  auto STAGE = [&](int jt, int bbuf, int part) {
    const int h = part & 1;
    const bool isB = part >= 2;
    const int tap = jt >> 3;              // 0..2 (conv tap; 8 K-tiles per tap)
    const int kin = (jt & 7) << 6;        // in-channel base within tap
    #pragma unroll
    for (int q = 0; q < 2; ++q) {
      const int Ll = q * 8192 + tid * 16;                    // linear dest in half
      const int Pl = Ll ^ (((Ll >> 9) & 1) << 5);            // inverse swizzle -> logical
      const int row = Pl >> 7;                               // 0..127
      const int kel = (Pl & 127) >> 1;                       // 0..63 (x8 aligned)
      char* ldsb = smem + bbuf * 65536 + (isB ? 32768 : 0) + h * 16384
                 + q * 8192 + (tid & ~63) * 16;              // wave-uniform base
      const ushort_t* src;
      if (isB) src = Wp + (size_t)(n0 + h * 128 + row) * KDIM + jt * 64 + kel;
      else     src = Ap + (size_t)(Arow0 + h * 128 + row + (tap - 1)) * 512 + kin + kel;
      gload_lds16(src, ldsb);
    }
  };
  // swizzled ds_read of one bf16x8 fragment
  auto LDA = [&](int bbuf, int fr, int ks) -> bf16x8 {
    const int R = wr * 128 + fr * 16 + l15;
    const int kb = (ks * 64 + l4 * 16) ^ (((R >> 2) & 1) << 5);
    return *(const bf16x8*)(smem + bbuf * 65536 + R * 128 + kb);
  };
  auto LDB = [&](int bbuf, int fc, int ks) -> bf16x8 {
    const int R = wc * 64 + fc * 16 + l15;
    const int kb = (ks * 64 + l4 * 16) ^ (((R >> 2) & 1) << 5);
    return *(const bf16x8*)(smem + bbuf * 65536 + 32768 + R * 128 + kb);
  };

  // prologue: stage tile 0 (buf0) then tile 1 (buf1); wait own tile-0 stores (8 newer allowed)
  #pragma unroll
  for (int part = 0; part < 4; ++part) STAGE(0, 0, part);
  #pragma unroll
  for (int part = 0; part < 4; ++part) STAGE(1, 1, part);
  asm volatile("s_waitcnt vmcnt(8)" ::: "memory");
  __builtin_amdgcn_s_barrier();

  for (int s = 0; s < 24; ++s) {
    const int bb = s & 1;
    bf16x8 bF[4][2];
    #pragma unroll
    for (int p = 0; p < 4; ++p) {
      // ds-reads for this phase's quadrant (A: frag rows 2p,2p+1; B once per K-tile)
      bf16x8 aF[2][2];
      #pragma unroll
      for (int i = 0; i < 2; ++i)
        #pragma unroll
        for (int ks = 0; ks < 2; ++ks)
          aF[i][ks] = LDA(bb, 2 * p + i, ks);
      if (p == 0) {
        #pragma unroll
        for (int fc = 0; fc < 4; ++fc)
          #pragma unroll
          for (int ks = 0; ks < 2; ++ks)
            bF[fc][ks] = LDB(bb, fc, ks);
      }
      // stage half-tile p of tile s+1 into the non-read buffer
      if (s >= 1 && s <= 22) STAGE(s + 1, bb ^ 1, p);
      __builtin_amdgcn_s_barrier();
      __builtin_amdgcn_s_setprio(1);
      #pragma unroll
      for (int ks = 0; ks < 2; ++ks)
        #pragma unroll
        for (int i = 0; i < 2; ++i)
          #pragma unroll
          for (int fc = 0; fc < 4; ++fc)
            acc[2 * p + i][fc] = __builtin_amdgcn_mfma_f32_16x16x32_bf16(
                aF[i][ks], bF[fc][ks], acc[2 * p + i][fc], 0, 0, 0);
      __builtin_amdgcn_s_setprio(0);
      if (p == 3) asm volatile("s_waitcnt vmcnt(0)" ::: "memory");  // tile s+1 landed
      __builtin_amdgcn_s_barrier();
    }
  }

  // epilogue: bias + relu -> bf16, direct stores
  float bvv[4];
  #pragma unroll
  for (int fc = 0; fc < 4; ++fc) bvv[fc] = bp[n0 + wc * 64 + fc * 16 + l15];
  #pragma unroll
  for (int fr = 0; fr < 8; ++fr) {
    const int row0 = m0 + wr * 128 + fr * 16 + l4 * 4;
    #pragma unroll
    for (int fc = 0; fc < 4; ++fc) {
      const int col = n0 + wc * 64 + fc * 16 + l15;
      #pragma unroll
      for (int r = 0; r < 4; ++r) {
        float v = acc[fr][fc][r] + bvv[fc];
        v = v > 0.f ? v : 0.f;
        Hp[(size_t)(row0 + r) * 512 + col] = f2bf(v);
      }
    }
  }
}

// ---------------- batched LayerNorm (wave per row) -> padded bf16 buffers
__global__ __launch_bounds__(256) void k_ln_mid(const ushort_t* __restrict__ Hh,
                                                const float* __restrict__ g, const float* __restrict__ bb,
                                                ushort_t* __restrict__ lnp0, ushort_t* __restrict__ lnp1,
                                                ushort_t* __restrict__ lnp2) {
  const int rr = blockIdx.x * 4 + (threadIdx.x >> 6);   // 0..3*NB_M-1
  const int pred = rr >> 14, m = rr & (NB_M - 1);
  const int lane = threadIdx.x & 63;
  const float* gp = g + pred * 512;
  const float* bp = bb + pred * 512;
  ushort_t* dst = (pred == 0) ? lnp0 : ((pred == 1) ? lnp1 : lnp2);
  bf16x8 v = *(const bf16x8*)(Hh + (size_t)rr * 512 + lane * 8);
  float xv[8];
  float s = 0.f;
  #pragma unroll
  for (int j = 0; j < 8; ++j) { xv[j] = bf2f((ushort_t)v[j]); s += xv[j]; }
  #pragma unroll
  for (int mm = 32; mm >= 1; mm >>= 1) s += __shfl_xor(s, mm, 64);
  const float mean = s * (1.f / 512.f);
  float vs = 0.f;
  #pragma unroll
  for (int j = 0; j < 8; ++j) { float d = xv[j] - mean; vs += d * d; }
  #pragma unroll
  for (int mm = 32; mm >= 1; mm >>= 1) vs += __shfl_xor(vs, mm, 64);
  const float rstd = rsqrtf(vs * (1.f / 512.f) + 1e-5f);
  const float4 g0 = ((const float4*)(gp + lane * 8))[0];
  const float4 g1 = ((const float4*)(gp + lane * 8))[1];
  const float4 b0 = ((const float4*)(bp + lane * 8))[0];
  const float4 b1 = ((const float4*)(bp + lane * 8))[1];
  const float gg[8] = {g0.x, g0.y, g0.z, g0.w, g1.x, g1.y, g1.z, g1.w};
  const float bv[8] = {b0.x, b0.y, b0.z, b0.w, b1.x, b1.y, b1.z, b1.w};
  bf16x8 o;
  #pragma unroll
  for (int j = 0; j < 8; ++j) o[j] = (short)f2bf((xv[j] - mean) * rstd * gg[j] + bv[j]);
  const int bidx = m >> 9, t = m & 511;
  *(bf16x8*)(dst + ((size_t)(bidx * 514 + t + 1)) * 512 + lane * 8) = o;
}

// ---------------- batched LayerNorm + linear proj + mask -> 3 pred outputs (contiguous)
__global__ __launch_bounds__(256) void k_ln_fin(const ushort_t* __restrict__ Hh,
                                                const float* __restrict__ g, const float* __restrict__ bb,
                                                const float* __restrict__ lw, const float* __restrict__ lbp,
                                                const unsigned char* __restrict__ mask,
                                                float* __restrict__ outp) {
  const int rr = blockIdx.x * 4 + (threadIdx.x >> 6);
  const int pred = rr >> 14, m = rr & (NB_M - 1);
  const int lane = threadIdx.x & 63;
  const float* gp = g + pred * 512;
  const float* bp = bb + pred * 512;
  const float* wp = lw + pred * 512;
  bf16x8 v = *(const bf16x8*)(Hh + (size_t)rr * 512 + lane * 8);
  float xv[8];
  float s = 0.f;
  #pragma unroll
  for (int j = 0; j < 8; ++j) { xv[j] = bf2f((ushort_t)v[j]); s += xv[j]; }
  #pragma unroll
  for (int mm = 32; mm >= 1; mm >>= 1) s += __shfl_xor(s, mm, 64);
  const float mean = s * (1.f / 512.f);
  float vs = 0.f;
  #pragma unroll
  for (int j = 0; j < 8; ++j) { float d = xv[j] - mean; vs += d * d; }
  #pragma unroll
  for (int mm = 32; mm >= 1; mm >>= 1) vs += __shfl_xor(vs, mm, 64);
  const float rstd = rsqrtf(vs * (1.f / 512.f) + 1e-5f);
  const float4 g0 = ((const float4*)(gp + lane * 8))[0];
  const float4 g1 = ((const float4*)(gp + lane * 8))[1];
  const float4 b0 = ((const float4*)(bp + lane * 8))[0];
  const float4 b1 = ((const float4*)(bp + lane * 8))[1];
  const float4 w0 = ((const float4*)(wp + lane * 8))[0];
  const float4 w1 = ((const float4*)(wp + lane * 8))[1];
  const float gg[8] = {g0.x, g0.y, g0.z, g0.w, g1.x, g1.y, g1.z, g1.w};
  const float bv[8] = {b0.x, b0.y, b0.z, b0.w, b1.x, b1.y, b1.z, b1.w};
  const float ww[8] = {w0.x, w0.y, w0.z, w0.w, w1.x, w1.y, w1.z, w1.w};
  float dot = 0.f;
  #pragma unroll
  for (int j = 0; j < 8; ++j) dot += ((xv[j] - mean) * rstd * gg[j] + bv[j]) * ww[j];
  #pragma unroll
  for (int mm = 32; mm >= 1; mm >>= 1) dot += __shfl_xor(dot, mm, 64);
  if (lane == 0) {
    float val = dot + lbp[pred];
    if (mask[m]) val = 0.f;
    outp[pred * NB_M + m] = val;
  }
}

// ---------------- length regulator: 1024 blocks (b x 64-frame chunk), cum in LDS,
//                  wave-per-frame copy, fused mel_mask write
__global__ __launch_bounds__(256) void k_regulate(const ushort_t* __restrict__ x3b, const int* __restrict__ cum,
                                                  float* __restrict__ xout, float* __restrict__ mmask) {
  __shared__ int c[512];
  const int blk = blockIdx.x;            // 0..1023
  const int b = blk >> 5, chunk = blk & 31;
  const int tid = threadIdx.x, lane = tid & 63, w = tid >> 6;
  c[tid] = cum[b * NB_T + tid];
  c[tid + 256] = cum[b * NB_T + tid + 256];
  __syncthreads();
  int ml = c[511]; ml = ml < MAXL ? ml : MAXL;
  const int f0 = chunk * 64 + w * 16;
  for (int i = 0; i < 16; ++i) {
    const int f = f0 + i;
    float o[8] = {0.f, 0.f, 0.f, 0.f, 0.f, 0.f, 0.f, 0.f};
    if (f < ml) {
      int lo = 0, hi = 512;
      while (lo < hi) { int mid = (lo + hi) >> 1; if (c[mid] <= f) lo = mid + 1; else hi = mid; }
      if (lo > 511) lo = 511;
      bf16x8 vv = *(const bf16x8*)(x3b + ((size_t)(b * NB_T + lo)) * 512 + lane * 8);
      #pragma unroll
      for (int j = 0; j < 8; ++j) o[j] = bf2f((ushort_t)vv[j]);
    }
    float* dst = xout + ((size_t)(b * MAXL + f)) * 512 + lane * 8;
    ((float4*)dst)[0] = make_float4(o[0], o[1], o[2], o[3]);
    ((float4*)dst)[1] = make_float4(o[4], o[5], o[6], o[7]);
    if (lane == 0) mmask[b * MAXL + f] = (f >= ml) ? 1.0f : 0.0f;
  }
}

extern "C" void kernel_launch(void* const* d_in, const int* in_sizes, int n_in,
                              void* d_out, int out_size, void* d_ws, size_t ws_size,
                              hipStream_t stream) {
  const float* x        = (const float*)d_in[0];
  const unsigned char* src_mask = (const unsigned char*)d_in[1];
  const int* duration   = (const int*)d_in[2];
  const float* pitch_t  = (const float*)d_in[3];
  const float* energy_t = (const float*)d_in[4];
  const float* conv1_w  = (const float*)d_in[5];
  const float* conv1_b  = (const float*)d_in[6];
  const float* ln1_g    = (const float*)d_in[7];
  const float* ln1_b    = (const float*)d_in[8];
  const float* conv2_w  = (const float*)d_in[9];
  const float* conv2_b  = (const float*)d_in[10];
  const float* ln2_g    = (const float*)d_in[11];
  const float* ln2_b    = (const float*)d_in[12];
  const float* lin_w    = (const float*)d_in[13];
  const float* lin_b    = (const float*)d_in[14];
  const float* pbins    = (const float*)d_in[15];
  const float* ebins    = (const float*)d_in[16];
  const float* ptab     = (const float*)d_in[17];
  const float* etab     = (const float*)d_in[18];

  char* ws = (char*)d_ws;
  ushort_t* wt1    = (ushort_t*)(ws + 0);             //  4,718,592
  ushort_t* wt2    = (ushort_t*)(ws + 4718592);       //  4,718,592
  ushort_t* xb_pad = (ushort_t*)(ws + 9437184);       // 16,842,752  (aliased: lnp0)
  ushort_t* x2pad  = (ushort_t*)(ws + 26279936);      // 16,842,752  (aliased: lnp1)
  ushort_t* lnp2   = (ushort_t*)(ws + 43122688);      // 16,842,752
  ushort_t* hbuf   = (ushort_t*)(ws + 59965440);      // 50,331,648  (3 preds)
  ushort_t* x3b    = (ushort_t*)(ws + 110297088);     // 16,777,216
  int*      cum    = (int*)     (ws + 127074304);     //     65,536

  float* out      = (float*)d_out;
  float* o_xout   = out;                       // 33,554,432
  float* o_preds  = out + 33554432;            // 3 x 16384 (logd, pitch, energy)
  float* o_mellen = o_preds + 3 * NB_M;        // 32
  float* o_mmask  = o_mellen + 32;             // 65,536

  k_cum<<<NB_B, 512, 0, stream>>>(duration, src_mask, cum, o_mellen);
  k_wt<<<dim3(64, 18), 256, 0, stream>>>(conv1_w, conv2_w, wt1, wt2);
  k_prep<<<NB_B * 514, 256, 0, stream>>>(x, pitch_t, energy_t, pbins, ebins, ptab, etab,
                                         xb_pad, x2pad, lnp2, x3b);

  // conv1 for all 3 predictors (pred0,1 read xb_pad; pred2 reads x2pad)
  k_gemm<<<384, 512, 131072, stream>>>(xb_pad, xb_pad, x2pad, wt1, conv1_b, hbuf);
  // LN1 for all 3 (writes padded inputs for conv2; lnp0/lnp1 alias xb_pad/x2pad)
  k_ln_mid<<<3 * NB_M / 4, 256, 0, stream>>>(hbuf, ln1_g, ln1_b, xb_pad, x2pad, lnp2);
  // conv2 for all 3
  k_gemm<<<384, 512, 131072, stream>>>(xb_pad, x2pad, lnp2, wt2, conv2_b, hbuf);
  // LN2 + linear + mask -> all 3 predictions
  k_ln_fin<<<3 * NB_M / 4, 256, 0, stream>>>(hbuf, ln2_g, ln2_b, lin_w, lin_b, src_mask, o_preds);

  k_regulate<<<1024, 256, 0, stream>>>(x3b, cum, o_xout, o_mmask);
}

// Round 8
// 482.002 us; speedup vs baseline: 1.0427x; 1.0427x over previous
//
#include <hip/hip_runtime.h>
#include <hip/hip_bf16.h>

typedef unsigned short ushort_t;
typedef unsigned int uint_t;
typedef __attribute__((ext_vector_type(8))) short bf16x8;
typedef __attribute__((ext_vector_type(4))) float f32x4;

#define NB_T 512
#define NB_B 32
#define NB_M (NB_B * NB_T)     // 16384
#define KDIM 1536
#define MAXL 2048
#define EPI_STRIDE 144

__device__ __forceinline__ ushort_t f2bf(float f) {
  __hip_bfloat16 h = __float2bfloat16(f);
  return *reinterpret_cast<ushort_t*>(&h);
}
__device__ __forceinline__ float bf2f(ushort_t u) {
  __hip_bfloat16 h;
  *reinterpret_cast<ushort_t*>(&h) = u;
  return __bfloat162float(h);
}
__device__ __forceinline__ uint_t pack2(float a, float b) {
  return (uint_t)f2bf(a) | ((uint_t)f2bf(b) << 16);
}
__device__ __forceinline__ void gload_lds16(const void* g, void* l) {
  __builtin_amdgcn_global_load_lds((const __attribute__((address_space(1))) void*)g,
                                   (__attribute__((address_space(3))) void*)l, 16, 0, 0);
}

// ---------------- weight transpose (both convs in one dispatch):
// w[pk][i][o] f32 -> wt[p][o][kk*512+i] bf16
__global__ __launch_bounds__(256) void k_wt(const float* __restrict__ w1, const float* __restrict__ w2,
                                            ushort_t* __restrict__ wt1, ushort_t* __restrict__ wt2) {
  __shared__ float tile[64][65];
  int g = blockIdx.y;                 // 0..17
  const float* wsrc;
  ushort_t* wdst;
  if (g < 9) { wsrc = w1; wdst = wt1; } else { wsrc = w2; wdst = wt2; g -= 9; }
  const int p = g / 3, kk = g % 3;
  const int ot = (blockIdx.x & 7) * 64;
  const int it = (blockIdx.x >> 3) * 64;
  const int tx = threadIdx.x & 63;
  const int ty = threadIdx.x >> 6;
  const float* src = wsrc + (size_t)g * 512 * 512;
  #pragma unroll
  for (int r = ty; r < 64; r += 4)
    tile[r][tx] = src[(size_t)(it + r) * 512 + ot + tx];
  __syncthreads();
  #pragma unroll
  for (int r = ty; r < 64; r += 4)
    wdst[((size_t)(p * 512 + ot + r)) * KDIM + kk * 512 + it + tx] = f2bf(tile[tx][r]);
}

// ---------------- per-batch cumsum of masked duration + mel_len
__global__ __launch_bounds__(512) void k_cum(const int* __restrict__ dur, const unsigned char* __restrict__ mask,
                                             int* __restrict__ cum, float* __restrict__ mel_len_out) {
  __shared__ int s[512];
  const int b = blockIdx.x, t = threadIdx.x;
  int d = mask[b * NB_T + t] ? 0 : dur[b * NB_T + t];
  s[t] = d;
  __syncthreads();
  for (int off = 1; off < 512; off <<= 1) {
    int v = (t >= off) ? s[t - off] : 0;
    __syncthreads();
    s[t] += v;
    __syncthreads();
  }
  cum[b * NB_T + t] = s[t];
  if (t == 0) {
    int ml = s[511]; ml = ml < MAXL ? ml : MAXL;
    mel_len_out[b] = (float)ml;
  }
}

// ---------------- fused prep (+bucketize): xb_pad = bf(x), x2pad = bf(x + ptab[pi]),
//                  x3b = bf(x + ptab + etab), zero pad rows (xb/x2/lnp2)
__global__ __launch_bounds__(256) void k_prep(const float* __restrict__ x,
                                              const float* __restrict__ pt, const float* __restrict__ et,
                                              const float* __restrict__ pb, const float* __restrict__ eb,
                                              const float* __restrict__ ptab, const float* __restrict__ etab,
                                              ushort_t* __restrict__ xb_pad, ushort_t* __restrict__ x2pad,
                                              ushort_t* __restrict__ lnp2, ushort_t* __restrict__ x3b) {
  const int rp = blockIdx.x;               // 0..B*514-1
  const int b = rp / 514, j = rp % 514;
  const int tid = threadIdx.x;             // 2 elements each
  if (j == 0 || j == 513) {
    ((uint_t*)(xb_pad + (size_t)rp * 512))[tid] = 0u;
    ((uint_t*)(x2pad + (size_t)rp * 512))[tid] = 0u;
    ((uint_t*)(lnp2 + (size_t)rp * 512))[tid] = 0u;
    return;
  }
  const int m = b * NB_T + j - 1;
  float v = pt[m];
  int lo = 0, hi = 255;
  while (lo < hi) { int mid = (lo + hi) >> 1; if (pb[mid] < v) lo = mid + 1; else hi = mid; }
  const int pi = lo;
  v = et[m]; lo = 0; hi = 255;
  while (lo < hi) { int mid = (lo + hi) >> 1; if (eb[mid] < v) lo = mid + 1; else hi = mid; }
  const int ei = lo;

  const float2 xv = ((const float2*)(x + (size_t)m * 512))[tid];
  const float2 pv = ((const float2*)(ptab + (size_t)pi * 512))[tid];
  const float2 ev = ((const float2*)(etab + (size_t)ei * 512))[tid];
  ((uint_t*)(xb_pad + (size_t)rp * 512))[tid] = pack2(xv.x, xv.y);
  const float ax = xv.x + pv.x, ay = xv.y + pv.y;
  ((uint_t*)(x2pad + (size_t)rp * 512))[tid] = pack2(ax, ay);
  ((uint_t*)(x3b + (size_t)m * 512))[tid] = pack2(ax + ev.x, ay + ev.y);
}

// ---------------- 256x256 8-phase conv-as-GEMM
// 512 thr, 8 waves (2Mx4N), BK=64, 24 K-tiles, dyn LDS 128 KiB (2 K-tile bufs).
// Row-keyed 3-bit XOR swizzle (byte ^= (row&7)<<4): linear LDS dest +
// inverse-swizzled global src + swizzled ds_read (involution, rows 128B).
__global__ __launch_bounds__(512, 1) void k_gemm(const ushort_t* __restrict__ A0,
                                                 const ushort_t* __restrict__ A1,
                                                 const ushort_t* __restrict__ A2,
                                                 const ushort_t* __restrict__ Wt,
                                                 const float* __restrict__ bias,
                                                 ushort_t* __restrict__ H) {
  extern __shared__ char smem[];          // [2 bufs][A 32KB | B 32KB]
  const int tid = threadIdx.x;
  const int lane = tid & 63, wid = tid >> 6;
  const int wr = wid >> 2, wc = wid & 3;  // 2M x 4N wave grid
  const int l15 = lane & 15, l4 = lane >> 4;

  // bijective XCD-chunked swizzle: 384 blocks = 8 x 48
  const int bid = blockIdx.x;
  const int logical = (bid & 7) * 48 + (bid >> 3);
  const int pred = logical >> 7;          // 0..2
  const int tl = logical & 127;
  const int mt = tl >> 1, nt = tl & 1;
  const int m0 = mt << 8, n0 = nt << 8;
  const int b = m0 >> 9, t0 = m0 & 511;
  const long Arow0 = (long)b * 514 + t0 + 1;

  const ushort_t* Ap = (pred == 0) ? A0 : ((pred == 1) ? A1 : A2);
  const ushort_t* Wp = Wt + (size_t)pred * 512 * KDIM;
  const float* bp = bias + pred * 512;
  ushort_t* Hp = H + (size_t)pred * NB_M * 512;

  f32x4 acc[8][4];
  #pragma unroll
  for (int i = 0; i < 8; ++i)
    #pragma unroll
    for (int j = 0; j < 4; ++j) acc[i][j] = (f32x4)0.f;

  // stage one half-tile (16 KB): part 0=A-h0, 1=A-h1, 2=B-h0, 3=B-h1
  auto STAGE = [&](int jt, int bbuf, int part) {
    const int h = part & 1;
    const bool isB = part >= 2;
    const int tap = jt >> 3;              // 0..2 (conv tap; 8 K-tiles per tap)
    const int kin = (jt & 7) << 6;        // in-channel base within tap
    #pragma unroll
    for (int q = 0; q < 2; ++q) {
      const int Ll = q * 8192 + tid * 16;                    // linear dest in half
      const int row = Ll >> 7;                               // 0..127
      const int Pl = Ll ^ ((row & 7) << 4);                  // inverse swizzle -> logical
      const int kel = (Pl & 127) >> 1;                       // 0..63 (x8 aligned)
      char* ldsb = smem + bbuf * 65536 + (isB ? 32768 : 0) + h * 16384
                 + q * 8192 + (tid & ~63) * 16;              // wave-uniform base
      const ushort_t* src;
      if (isB) src = Wp + (size_t)(n0 + h * 128 + row) * KDIM + jt * 64 + kel;
      else     src = Ap + (size_t)(Arow0 + h * 128 + row + (tap - 1)) * 512 + kin + kel;
      gload_lds16(src, ldsb);
    }
  };
  // swizzled ds_read of one bf16x8 fragment
  auto LDA = [&](int bbuf, int fr, int ks) -> bf16x8 {
    const int R = wr * 128 + fr * 16 + l15;
    const int kb = (ks * 64 + l4 * 16) ^ ((R & 7) << 4);
    return *(const bf16x8*)(smem + bbuf * 65536 + R * 128 + kb);
  };
  auto LDB = [&](int bbuf, int fc, int ks) -> bf16x8 {
    const int R = wc * 64 + fc * 16 + l15;
    const int kb = (ks * 64 + l4 * 16) ^ ((R & 7) << 4);
    return *(const bf16x8*)(smem + bbuf * 65536 + 32768 + R * 128 + kb);
  };

  // prologue: stage tile 0 (buf0) then tile 1 (buf1); wait tile-0 (8 newer allowed)
  #pragma unroll
  for (int part = 0; part < 4; ++part) STAGE(0, 0, part);
  #pragma unroll
  for (int part = 0; part < 4; ++part) STAGE(1, 1, part);
  asm volatile("s_waitcnt vmcnt(8)" ::: "memory");
  __builtin_amdgcn_s_barrier();

  for (int s = 0; s < 24; ++s) {
    const int bb = s & 1;
    bf16x8 bF[4][2];
    #pragma unroll
    for (int p = 0; p < 4; ++p) {
      bf16x8 aF[2][2];
      #pragma unroll
      for (int i = 0; i < 2; ++i)
        #pragma unroll
        for (int ks = 0; ks < 2; ++ks)
          aF[i][ks] = LDA(bb, 2 * p + i, ks);
      if (p == 0) {
        #pragma unroll
        for (int fc = 0; fc < 4; ++fc)
          #pragma unroll
          for (int ks = 0; ks < 2; ++ks)
            bF[fc][ks] = LDB(bb, fc, ks);
      }
      // stage tile s+1 into the non-read buffer: parts {0},{1},{2,3} in phases 0,1,2
      if (s >= 1 && s <= 22) {
        if (p == 0) STAGE(s + 1, bb ^ 1, 0);
        else if (p == 1) STAGE(s + 1, bb ^ 1, 1);
        else if (p == 2) { STAGE(s + 1, bb ^ 1, 2); STAGE(s + 1, bb ^ 1, 3); }
      }
      __builtin_amdgcn_s_barrier();
      __builtin_amdgcn_s_setprio(1);
      #pragma unroll
      for (int ks = 0; ks < 2; ++ks)
        #pragma unroll
        for (int i = 0; i < 2; ++i)
          #pragma unroll
          for (int fc = 0; fc < 4; ++fc)
            acc[2 * p + i][fc] = __builtin_amdgcn_mfma_f32_16x16x32_bf16(
                aF[i][ks], bF[fc][ks], acc[2 * p + i][fc], 0, 0, 0);
      __builtin_amdgcn_s_setprio(0);
      if (p == 3) asm volatile("s_waitcnt vmcnt(0)" ::: "memory");  // tile s+1 landed
      __builtin_amdgcn_s_barrier();
    }
  }

  // epilogue: bias + relu -> bf16 via LDS bounce (stride 144), coalesced 16B stores
  short* sm = (short*)smem;
  float bvv[4];
  #pragma unroll
  for (int fc = 0; fc < 4; ++fc) bvv[fc] = bp[n0 + wc * 64 + fc * 16 + l15];
  #pragma unroll
  for (int fr = 0; fr < 8; ++fr) {
    const int rowb = wr * 128 + fr * 16 + l4 * 4;
    #pragma unroll
    for (int fc = 0; fc < 4; ++fc) {
      const int col = wc * 64 + fc * 16 + l15;
      #pragma unroll
      for (int r = 0; r < 4; ++r) {
        float v = acc[fr][fc][r] + bvv[fc];
        v = v > 0.f ? v : 0.f;
        sm[(rowb + r) * EPI_STRIDE + col] = (short)f2bf(v);
      }
    }
  }
  __syncthreads();
  #pragma unroll
  for (int s2 = 0; s2 < 8; ++s2) {
    const int chunk = tid + s2 * 512;       // 0..4095
    const int row = chunk >> 4, c8 = (chunk & 15) * 8;
    bf16x8 vv = *(const bf16x8*)&sm[row * EPI_STRIDE + c8];
    *(bf16x8*)(Hp + (size_t)(m0 + row) * 512 + n0 + c8) = vv;
  }
}

// ---------------- batched LayerNorm (wave per row) -> padded bf16 buffers
__global__ __launch_bounds__(256) void k_ln_mid(const ushort_t* __restrict__ Hh,
                                                const float* __restrict__ g, const float* __restrict__ bb,
                                                ushort_t* __restrict__ lnp0, ushort_t* __restrict__ lnp1,
                                                ushort_t* __restrict__ lnp2) {
  const int rr = blockIdx.x * 4 + (threadIdx.x >> 6);   // 0..3*NB_M-1
  const int pred = rr >> 14, m = rr & (NB_M - 1);
  const int lane = threadIdx.x & 63;
  const float* gp = g + pred * 512;
  const float* bp = bb + pred * 512;
  ushort_t* dst = (pred == 0) ? lnp0 : ((pred == 1) ? lnp1 : lnp2);
  bf16x8 v = *(const bf16x8*)(Hh + (size_t)rr * 512 + lane * 8);
  float xv[8];
  float s = 0.f;
  #pragma unroll
  for (int j = 0; j < 8; ++j) { xv[j] = bf2f((ushort_t)v[j]); s += xv[j]; }
  #pragma unroll
  for (int mm = 32; mm >= 1; mm >>= 1) s += __shfl_xor(s, mm, 64);
  const float mean = s * (1.f / 512.f);
  float vs = 0.f;
  #pragma unroll
  for (int j = 0; j < 8; ++j) { float d = xv[j] - mean; vs += d * d; }
  #pragma unroll
  for (int mm = 32; mm >= 1; mm >>= 1) vs += __shfl_xor(vs, mm, 64);
  const float rstd = rsqrtf(vs * (1.f / 512.f) + 1e-5f);
  const float4 g0 = ((const float4*)(gp + lane * 8))[0];
  const float4 g1 = ((const float4*)(gp + lane * 8))[1];
  const float4 b0 = ((const float4*)(bp + lane * 8))[0];
  const float4 b1 = ((const float4*)(bp + lane * 8))[1];
  const float gg[8] = {g0.x, g0.y, g0.z, g0.w, g1.x, g1.y, g1.z, g1.w};
  const float bv[8] = {b0.x, b0.y, b0.z, b0.w, b1.x, b1.y, b1.z, b1.w};
  bf16x8 o;
  #pragma unroll
  for (int j = 0; j < 8; ++j) o[j] = (short)f2bf((xv[j] - mean) * rstd * gg[j] + bv[j]);
  const int bidx = m >> 9, t = m & 511;
  *(bf16x8*)(dst + ((size_t)(bidx * 514 + t + 1)) * 512 + lane * 8) = o;
}

// ---------------- batched LayerNorm + linear proj + mask -> 3 pred outputs (contiguous)
__global__ __launch_bounds__(256) void k_ln_fin(const ushort_t* __restrict__ Hh,
                                                const float* __restrict__ g, const float* __restrict__ bb,
                                                const float* __restrict__ lw, const float* __restrict__ lbp,
                                                const unsigned char* __restrict__ mask,
                                                float* __restrict__ outp) {
  const int rr = blockIdx.x * 4 + (threadIdx.x >> 6);
  const int pred = rr >> 14, m = rr & (NB_M - 1);
  const int lane = threadIdx.x & 63;
  const float* gp = g + pred * 512;
  const float* bp = bb + pred * 512;
  const float* wp = lw + pred * 512;
  bf16x8 v = *(const bf16x8*)(Hh + (size_t)rr * 512 + lane * 8);
  float xv[8];
  float s = 0.f;
  #pragma unroll
  for (int j = 0; j < 8; ++j) { xv[j] = bf2f((ushort_t)v[j]); s += xv[j]; }
  #pragma unroll
  for (int mm = 32; mm >= 1; mm >>= 1) s += __shfl_xor(s, mm, 64);
  const float mean = s * (1.f / 512.f);
  float vs = 0.f;
  #pragma unroll
  for (int j = 0; j < 8; ++j) { float d = xv[j] - mean; vs += d * d; }
  #pragma unroll
  for (int mm = 32; mm >= 1; mm >>= 1) vs += __shfl_xor(vs, mm, 64);
  const float rstd = rsqrtf(vs * (1.f / 512.f) + 1e-5f);
  const float4 g0 = ((const float4*)(gp + lane * 8))[0];
  const float4 g1 = ((const float4*)(gp + lane * 8))[1];
  const float4 b0 = ((const float4*)(bp + lane * 8))[0];
  const float4 b1 = ((const float4*)(bp + lane * 8))[1];
  const float4 w0 = ((const float4*)(wp + lane * 8))[0];
  const float4 w1 = ((const float4*)(wp + lane * 8))[1];
  const float gg[8] = {g0.x, g0.y, g0.z, g0.w, g1.x, g1.y, g1.z, g1.w};
  const float bv[8] = {b0.x, b0.y, b0.z, b0.w, b1.x, b1.y, b1.z, b1.w};
  const float ww[8] = {w0.x, w0.y, w0.z, w0.w, w1.x, w1.y, w1.z, w1.w};
  float dot = 0.f;
  #pragma unroll
  for (int j = 0; j < 8; ++j) dot += ((xv[j] - mean) * rstd * gg[j] + bv[j]) * ww[j];
  #pragma unroll
  for (int mm = 32; mm >= 1; mm >>= 1) dot += __shfl_xor(dot, mm, 64);
  if (lane == 0) {
    float val = dot + lbp[pred];
    if (mask[m]) val = 0.f;
    outp[pred * NB_M + m] = val;
  }
}

// ---------------- length regulator: 1024 blocks (b x 64-frame chunk), cum in LDS,
//                  wave-per-frame copy, fused mel_mask write
__global__ __launch_bounds__(256) void k_regulate(const ushort_t* __restrict__ x3b, const int* __restrict__ cum,
                                                  float* __restrict__ xout, float* __restrict__ mmask) {
  __shared__ int c[512];
  const int blk = blockIdx.x;            // 0..1023
  const int b = blk >> 5, chunk = blk & 31;
  const int tid = threadIdx.x, lane = tid & 63, w = tid >> 6;
  c[tid] = cum[b * NB_T + tid];
  c[tid + 256] = cum[b * NB_T + tid + 256];
  __syncthreads();
  int ml = c[511]; ml = ml < MAXL ? ml : MAXL;
  const int f0 = chunk * 64 + w * 16;
  for (int i = 0; i < 16; ++i) {
    const int f = f0 + i;
    float o[8] = {0.f, 0.f, 0.f, 0.f, 0.f, 0.f, 0.f, 0.f};
    if (f < ml) {
      int lo = 0, hi = 512;
      while (lo < hi) { int mid = (lo + hi) >> 1; if (c[mid] <= f) lo = mid + 1; else hi = mid; }
      if (lo > 511) lo = 511;
      bf16x8 vv = *(const bf16x8*)(x3b + ((size_t)(b * NB_T + lo)) * 512 + lane * 8);
      #pragma unroll
      for (int j = 0; j < 8; ++j) o[j] = bf2f((ushort_t)vv[j]);
    }
    float* dst = xout + ((size_t)(b * MAXL + f)) * 512 + lane * 8;
    ((float4*)dst)[0] = make_float4(o[0], o[1], o[2], o[3]);
    ((float4*)dst)[1] = make_float4(o[4], o[5], o[6], o[7]);
    if (lane == 0) mmask[b * MAXL + f] = (f >= ml) ? 1.0f : 0.0f;
  }
}

extern "C" void kernel_launch(void* const* d_in, const int* in_sizes, int n_in,
                              void* d_out, int out_size, void* d_ws, size_t ws_size,
                              hipStream_t stream) {
  const float* x        = (const float*)d_in[0];
  const unsigned char* src_mask = (const unsigned char*)d_in[1];
  const int* duration   = (const int*)d_in[2];
  const float* pitch_t  = (const float*)d_in[3];
  const float* energy_t = (const float*)d_in[4];
  const float* conv1_w  = (const float*)d_in[5];
  const float* conv1_b  = (const float*)d_in[6];
  const float* ln1_g    = (const float*)d_in[7];
  const float* ln1_b    = (const float*)d_in[8];
  const float* conv2_w  = (const float*)d_in[9];
  const float* conv2_b  = (const float*)d_in[10];
  const float* ln2_g    = (const float*)d_in[11];
  const float* ln2_b    = (const float*)d_in[12];
  const float* lin_w    = (const float*)d_in[13];
  const float* lin_b    = (const float*)d_in[14];
  const float* pbins    = (const float*)d_in[15];
  const float* ebins    = (const float*)d_in[16];
  const float* ptab     = (const float*)d_in[17];
  const float* etab     = (const float*)d_in[18];

  char* ws = (char*)d_ws;
  ushort_t* wt1    = (ushort_t*)(ws + 0);             //  4,718,592
  ushort_t* wt2    = (ushort_t*)(ws + 4718592);       //  4,718,592
  ushort_t* xb_pad = (ushort_t*)(ws + 9437184);       // 16,842,752  (aliased: lnp0)
  ushort_t* x2pad  = (ushort_t*)(ws + 26279936);      // 16,842,752  (aliased: lnp1)
  ushort_t* lnp2   = (ushort_t*)(ws + 43122688);      // 16,842,752
  ushort_t* hbuf   = (ushort_t*)(ws + 59965440);      // 50,331,648  (3 preds)
  ushort_t* x3b    = (ushort_t*)(ws + 110297088);     // 16,777,216
  int*      cum    = (int*)     (ws + 127074304);     //     65,536

  float* out      = (float*)d_out;
  float* o_xout   = out;                       // 33,554,432
  float* o_preds  = out + 33554432;            // 3 x 16384 (logd, pitch, energy)
  float* o_mellen = o_preds + 3 * NB_M;        // 32
  float* o_mmask  = o_mellen + 32;             // 65,536

  k_cum<<<NB_B, 512, 0, stream>>>(duration, src_mask, cum, o_mellen);
  k_wt<<<dim3(64, 18), 256, 0, stream>>>(conv1_w, conv2_w, wt1, wt2);
  k_prep<<<NB_B * 514, 256, 0, stream>>>(x, pitch_t, energy_t, pbins, ebins, ptab, etab,
                                         xb_pad, x2pad, lnp2, x3b);

  // conv1 for all 3 predictors (pred0,1 read xb_pad; pred2 reads x2pad)
  k_gemm<<<384, 512, 131072, stream>>>(xb_pad, xb_pad, x2pad, wt1, conv1_b, hbuf);
  // LN1 for all 3 (writes padded inputs for conv2; lnp0/lnp1 alias xb_pad/x2pad)
  k_ln_mid<<<3 * NB_M / 4, 256, 0, stream>>>(hbuf, ln1_g, ln1_b, xb_pad, x2pad, lnp2);
  // conv2 for all 3
  k_gemm<<<384, 512, 131072, stream>>>(xb_pad, x2pad, lnp2, wt2, conv2_b, hbuf);
  // LN2 + linear + mask -> all 3 predictions
  k_ln_fin<<<3 * NB_M / 4, 256, 0, stream>>>(hbuf, ln2_g, ln2_b, lin_w, lin_b, src_mask, o_preds);

  k_regulate<<<1024, 256, 0, stream>>>(x3b, cum, o_xout, o_mmask);
}

// Round 9
// 480.803 us; speedup vs baseline: 1.0453x; 1.0025x over previous
//
#include <hip/hip_runtime.h>
#include <hip/hip_bf16.h>

typedef unsigned short ushort_t;
typedef unsigned int uint_t;
typedef __attribute__((ext_vector_type(8))) short bf16x8;
typedef __attribute__((ext_vector_type(4))) float f32x4;

#define NB_T 512
#define NB_B 32
#define NB_M (NB_B * NB_T)     // 16384
#define KDIM 1536
#define MAXL 2048
#define EPI_STRIDE 144         // shorts; 288 B rows, 128-wide tile -> col < 144 (no alias)

__device__ __forceinline__ ushort_t f2bf(float f) {
  __hip_bfloat16 h = __float2bfloat16(f);
  return *reinterpret_cast<ushort_t*>(&h);
}
__device__ __forceinline__ float bf2f(ushort_t u) {
  __hip_bfloat16 h;
  *reinterpret_cast<ushort_t*>(&h) = u;
  return __bfloat162float(h);
}
__device__ __forceinline__ uint_t pack2(float a, float b) {
  return (uint_t)f2bf(a) | ((uint_t)f2bf(b) << 16);
}
__device__ __forceinline__ void gload_lds16(const void* g, void* l) {
  __builtin_amdgcn_global_load_lds((const __attribute__((address_space(1))) void*)g,
                                   (__attribute__((address_space(3))) void*)l, 16, 0, 0);
}

// ---------------- weight transpose (both convs in one dispatch):
// w[pk][i][o] f32 -> wt[p][o][kk*512+i] bf16
__global__ __launch_bounds__(256) void k_wt(const float* __restrict__ w1, const float* __restrict__ w2,
                                            ushort_t* __restrict__ wt1, ushort_t* __restrict__ wt2) {
  __shared__ float tile[64][65];
  int g = blockIdx.y;                 // 0..17
  const float* wsrc;
  ushort_t* wdst;
  if (g < 9) { wsrc = w1; wdst = wt1; } else { wsrc = w2; wdst = wt2; g -= 9; }
  const int p = g / 3, kk = g % 3;
  const int ot = (blockIdx.x & 7) * 64;
  const int it = (blockIdx.x >> 3) * 64;
  const int tx = threadIdx.x & 63;
  const int ty = threadIdx.x >> 6;
  const float* src = wsrc + (size_t)g * 512 * 512;
  #pragma unroll
  for (int r = ty; r < 64; r += 4)
    tile[r][tx] = src[(size_t)(it + r) * 512 + ot + tx];
  __syncthreads();
  #pragma unroll
  for (int r = ty; r < 64; r += 4)
    wdst[((size_t)(p * 512 + ot + r)) * KDIM + kk * 512 + it + tx] = f2bf(tile[tx][r]);
}

// ---------------- per-batch cumsum of masked duration + mel_len
__global__ __launch_bounds__(512) void k_cum(const int* __restrict__ dur, const unsigned char* __restrict__ mask,
                                             int* __restrict__ cum, float* __restrict__ mel_len_out) {
  __shared__ int s[512];
  const int b = blockIdx.x, t = threadIdx.x;
  int d = mask[b * NB_T + t] ? 0 : dur[b * NB_T + t];
  s[t] = d;
  __syncthreads();
  for (int off = 1; off < 512; off <<= 1) {
    int v = (t >= off) ? s[t - off] : 0;
    __syncthreads();
    s[t] += v;
    __syncthreads();
  }
  cum[b * NB_T + t] = s[t];
  if (t == 0) {
    int ml = s[511]; ml = ml < MAXL ? ml : MAXL;
    mel_len_out[b] = (float)ml;
  }
}

// ---------------- fused prep (+bucketize): xb_pad = bf(x), x2pad = bf(x + ptab[pi]),
//                  x3b = bf(x + ptab + etab), zero pad rows (xb/x2/lnp2)
__global__ __launch_bounds__(256) void k_prep(const float* __restrict__ x,
                                              const float* __restrict__ pt, const float* __restrict__ et,
                                              const float* __restrict__ pb, const float* __restrict__ eb,
                                              const float* __restrict__ ptab, const float* __restrict__ etab,
                                              ushort_t* __restrict__ xb_pad, ushort_t* __restrict__ x2pad,
                                              ushort_t* __restrict__ lnp2, ushort_t* __restrict__ x3b) {
  const int rp = blockIdx.x;               // 0..B*514-1
  const int b = rp / 514, j = rp % 514;
  const int tid = threadIdx.x;             // 2 elements each
  if (j == 0 || j == 513) {
    ((uint_t*)(xb_pad + (size_t)rp * 512))[tid] = 0u;
    ((uint_t*)(x2pad + (size_t)rp * 512))[tid] = 0u;
    ((uint_t*)(lnp2 + (size_t)rp * 512))[tid] = 0u;
    return;
  }
  const int m = b * NB_T + j - 1;
  float v = pt[m];
  int lo = 0, hi = 255;
  while (lo < hi) { int mid = (lo + hi) >> 1; if (pb[mid] < v) lo = mid + 1; else hi = mid; }
  const int pi = lo;
  v = et[m]; lo = 0; hi = 255;
  while (lo < hi) { int mid = (lo + hi) >> 1; if (eb[mid] < v) lo = mid + 1; else hi = mid; }
  const int ei = lo;

  const float2 xv = ((const float2*)(x + (size_t)m * 512))[tid];
  const float2 pv = ((const float2*)(ptab + (size_t)pi * 512))[tid];
  const float2 ev = ((const float2*)(etab + (size_t)ei * 512))[tid];
  ((uint_t*)(xb_pad + (size_t)rp * 512))[tid] = pack2(xv.x, xv.y);
  const float ax = xv.x + pv.x, ay = xv.y + pv.y;
  ((uint_t*)(x2pad + (size_t)rp * 512))[tid] = pack2(ax, ay);
  ((uint_t*)(x3b + (size_t)m * 512))[tid] = pack2(ax + ev.x, ay + ev.y);
}

// ---------------- batched conv-as-GEMM, 128x128 tile, BK=32, TRIPLE-buffer ring,
// counted s_waitcnt vmcnt(4) per step (loads live across barriers; never drain-0 in loop)
__global__ __launch_bounds__(256) void k_gemm(const ushort_t* __restrict__ A0,
                                              const ushort_t* __restrict__ A1,
                                              const ushort_t* __restrict__ A2,
                                              const ushort_t* __restrict__ Wt,
                                              const float* __restrict__ bias,
                                              ushort_t* __restrict__ H) {
  __shared__ short smem[24576];   // ring: 3 bufs x (A 4096 + B 4096 shorts) = 48KB; epi reuses 36KB
  const int tid = threadIdx.x;
  const int lane = tid & 63, wid = tid >> 6;

  // bijective XCD-chunked swizzle: 1536 blocks, 192 per XCD
  const int h = blockIdx.x;
  const int logical = (h & 7) * 192 + (h >> 3);
  const int pred = logical >> 9;
  const int tile = logical & 511;
  const int mt = tile >> 2, nt = tile & 3;
  const int m0 = mt * 128, n0 = nt * 128;
  const int b = m0 >> 9, t0 = m0 & 511;
  const long Arow0 = (long)b * 514 + t0 + 1;

  const ushort_t* Ap = (pred == 0) ? A0 : ((pred == 1) ? A1 : A2);
  const ushort_t* Wp = Wt + (size_t)pred * 512 * KDIM;
  const float* bp = bias + pred * 512;
  ushort_t* Hp = H + (size_t)pred * NB_M * 512;

  const int subr = lane >> 2;
  const int ioff = (lane & 3) * 8;
  const int wr = wid >> 1, wc = wid & 1;
  const int lr = lane & 15, kg = lane >> 4;

  f32x4 acc[4][4];
  #pragma unroll
  for (int i = 0; i < 4; ++i)
    #pragma unroll
    for (int j = 0; j < 4; ++j) acc[i][j] = (f32x4)0.f;

  // stage K-tile kk into ring buffer buf (per wave: 2 A-issues + 2 B-issues = 4 in flight)
  auto STAGE = [&](int kk, int buf) {
    const int dt = (kk >> 4) - 1;          // conv tap: -1, 0, +1 (16 K-tiles per tap)
    const int i0 = (kk & 15) << 5;         // input-channel offset
    short* la = &smem[buf * 8192];
    short* lb = &smem[buf * 8192 + 4096];
    #pragma unroll
    for (int q = 0; q < 2; ++q) {
      const int chunk = wid * 2 + q;
      const int r = chunk * 16 + subr;
      gload_lds16(Ap + (size_t)(Arow0 + r + dt) * 512 + i0 + ioff, &la[chunk * 512]);
      gload_lds16(Wp + (size_t)(n0 + r) * KDIM + kk * 32 + ioff, &lb[chunk * 512]);
    }
  };

  // one K-step: reads rb, stages (kk+2)->sb, counted wait + raw barrier
  auto STEP = [&](int kk, int rb, int sb) {
    if (kk < 46) STAGE(kk + 2, sb);
    const short* la = &smem[rb * 8192];
    const short* lb = &smem[rb * 8192 + 4096];
    bf16x8 af[4], bfv[4];
    #pragma unroll
    for (int fi = 0; fi < 4; ++fi)
      af[fi] = *(const bf16x8*)&la[(wr * 64 + fi * 16 + lr) * 32 + kg * 8];
    #pragma unroll
    for (int fj = 0; fj < 4; ++fj)
      bfv[fj] = *(const bf16x8*)&lb[(wc * 64 + fj * 16 + lr) * 32 + kg * 8];
    #pragma unroll
    for (int fi = 0; fi < 4; ++fi)
      #pragma unroll
      for (int fj = 0; fj < 4; ++fj)
        acc[fi][fj] = __builtin_amdgcn_mfma_f32_16x16x32_bf16(af[fi], bfv[fj], acc[fi][fj], 0, 0, 0);
    if (kk < 46) asm volatile("s_waitcnt vmcnt(4)" ::: "memory");  // tile kk+1 landed; kk+2 in flight
    else         asm volatile("s_waitcnt vmcnt(0)" ::: "memory");  // drain tail
    __builtin_amdgcn_s_barrier();
    __builtin_amdgcn_sched_barrier(0);
  };

  // prologue: tiles 0,1 into bufs 0,1; wait tile 0 (tile 1 stays in flight)
  STAGE(0, 0);
  STAGE(1, 1);
  asm volatile("s_waitcnt vmcnt(4)" ::: "memory");
  __builtin_amdgcn_s_barrier();
  __builtin_amdgcn_sched_barrier(0);

  for (int j = 0; j < 16; ++j) {
    STEP(3 * j + 0, 0, 2);
    STEP(3 * j + 1, 1, 0);
    STEP(3 * j + 2, 2, 1);
  }

  // epilogue: bias + relu -> bf16 via LDS bounce (128 rows x stride 144), coalesced 16B stores
  float bvv[4];
  #pragma unroll
  for (int fj = 0; fj < 4; ++fj) bvv[fj] = bp[n0 + wc * 64 + fj * 16 + lr];
  #pragma unroll
  for (int fi = 0; fi < 4; ++fi) {
    const int rowb = wr * 64 + fi * 16 + kg * 4;
    #pragma unroll
    for (int fj = 0; fj < 4; ++fj) {
      const int col = wc * 64 + fj * 16 + lr;
      #pragma unroll
      for (int r = 0; r < 4; ++r) {
        float v = acc[fi][fj][r] + bvv[fj];
        v = v > 0.f ? v : 0.f;
        smem[(rowb + r) * EPI_STRIDE + col] = (short)f2bf(v);
      }
    }
  }
  __syncthreads();
  #pragma unroll
  for (int s2 = 0; s2 < 8; ++s2) {
    const int chunk = tid + s2 * 256;        // 0..2047 = 128 rows x 16 chunks
    const int row = chunk >> 4, c8 = (chunk & 15) * 8;
    bf16x8 vv = *(const bf16x8*)&smem[row * EPI_STRIDE + c8];
    *(bf16x8*)(Hp + (size_t)(m0 + row) * 512 + n0 + c8) = vv;
  }
}

// ---------------- batched LayerNorm (wave per row) -> padded bf16 buffers
__global__ __launch_bounds__(256) void k_ln_mid(const ushort_t* __restrict__ Hh,
                                                const float* __restrict__ g, const float* __restrict__ bb,
                                                ushort_t* __restrict__ lnp0, ushort_t* __restrict__ lnp1,
                                                ushort_t* __restrict__ lnp2) {
  const int rr = blockIdx.x * 4 + (threadIdx.x >> 6);   // 0..3*NB_M-1
  const int pred = rr >> 14, m = rr & (NB_M - 1);
  const int lane = threadIdx.x & 63;
  const float* gp = g + pred * 512;
  const float* bp = bb + pred * 512;
  ushort_t* dst = (pred == 0) ? lnp0 : ((pred == 1) ? lnp1 : lnp2);
  bf16x8 v = *(const bf16x8*)(Hh + (size_t)rr * 512 + lane * 8);
  float xv[8];
  float s = 0.f;
  #pragma unroll
  for (int j = 0; j < 8; ++j) { xv[j] = bf2f((ushort_t)v[j]); s += xv[j]; }
  #pragma unroll
  for (int mm = 32; mm >= 1; mm >>= 1) s += __shfl_xor(s, mm, 64);
  const float mean = s * (1.f / 512.f);
  float vs = 0.f;
  #pragma unroll
  for (int j = 0; j < 8; ++j) { float d = xv[j] - mean; vs += d * d; }
  #pragma unroll
  for (int mm = 32; mm >= 1; mm >>= 1) vs += __shfl_xor(vs, mm, 64);
  const float rstd = rsqrtf(vs * (1.f / 512.f) + 1e-5f);
  const float4 g0 = ((const float4*)(gp + lane * 8))[0];
  const float4 g1 = ((const float4*)(gp + lane * 8))[1];
  const float4 b0 = ((const float4*)(bp + lane * 8))[0];
  const float4 b1 = ((const float4*)(bp + lane * 8))[1];
  const float gg[8] = {g0.x, g0.y, g0.z, g0.w, g1.x, g1.y, g1.z, g1.w};
  const float bv[8] = {b0.x, b0.y, b0.z, b0.w, b1.x, b1.y, b1.z, b1.w};
  bf16x8 o;
  #pragma unroll
  for (int j = 0; j < 8; ++j) o[j] = (short)f2bf((xv[j] - mean) * rstd * gg[j] + bv[j]);
  const int bidx = m >> 9, t = m & 511;
  *(bf16x8*)(dst + ((size_t)(bidx * 514 + t + 1)) * 512 + lane * 8) = o;
}

// ---------------- batched LayerNorm + linear proj + mask -> 3 pred outputs (contiguous)
__global__ __launch_bounds__(256) void k_ln_fin(const ushort_t* __restrict__ Hh,
                                                const float* __restrict__ g, const float* __restrict__ bb,
                                                const float* __restrict__ lw, const float* __restrict__ lbp,
                                                const unsigned char* __restrict__ mask,
                                                float* __restrict__ outp) {
  const int rr = blockIdx.x * 4 + (threadIdx.x >> 6);
  const int pred = rr >> 14, m = rr & (NB_M - 1);
  const int lane = threadIdx.x & 63;
  const float* gp = g + pred * 512;
  const float* bp = bb + pred * 512;
  const float* wp = lw + pred * 512;
  bf16x8 v = *(const bf16x8*)(Hh + (size_t)rr * 512 + lane * 8);
  float xv[8];
  float s = 0.f;
  #pragma unroll
  for (int j = 0; j < 8; ++j) { xv[j] = bf2f((ushort_t)v[j]); s += xv[j]; }
  #pragma unroll
  for (int mm = 32; mm >= 1; mm >>= 1) s += __shfl_xor(s, mm, 64);
  const float mean = s * (1.f / 512.f);
  float vs = 0.f;
  #pragma unroll
  for (int j = 0; j < 8; ++j) { float d = xv[j] - mean; vs += d * d; }
  #pragma unroll
  for (int mm = 32; mm >= 1; mm >>= 1) vs += __shfl_xor(vs, mm, 64);
  const float rstd = rsqrtf(vs * (1.f / 512.f) + 1e-5f);
  const float4 g0 = ((const float4*)(gp + lane * 8))[0];
  const float4 g1 = ((const float4*)(gp + lane * 8))[1];
  const float4 b0 = ((const float4*)(bp + lane * 8))[0];
  const float4 b1 = ((const float4*)(bp + lane * 8))[1];
  const float4 w0 = ((const float4*)(wp + lane * 8))[0];
  const float4 w1 = ((const float4*)(wp + lane * 8))[1];
  const float gg[8] = {g0.x, g0.y, g0.z, g0.w, g1.x, g1.y, g1.z, g1.w};
  const float bv[8] = {b0.x, b0.y, b0.z, b0.w, b1.x, b1.y, b1.z, b1.w};
  const float ww[8] = {w0.x, w0.y, w0.z, w0.w, w1.x, w1.y, w1.z, w1.w};
  float dot = 0.f;
  #pragma unroll
  for (int j = 0; j < 8; ++j) dot += ((xv[j] - mean) * rstd * gg[j] + bv[j]) * ww[j];
  #pragma unroll
  for (int mm = 32; mm >= 1; mm >>= 1) dot += __shfl_xor(dot, mm, 64);
  if (lane == 0) {
    float val = dot + lbp[pred];
    if (mask[m]) val = 0.f;
    outp[pred * NB_M + m] = val;
  }
}

// ---------------- length regulator: 1024 blocks (b x 64-frame chunk), cum in LDS,
//                  wave-per-frame copy, fused mel_mask write
__global__ __launch_bounds__(256) void k_regulate(const ushort_t* __restrict__ x3b, const int* __restrict__ cum,
                                                  float* __restrict__ xout, float* __restrict__ mmask) {
  __shared__ int c[512];
  const int blk = blockIdx.x;            // 0..1023
  const int b = blk >> 5, chunk = blk & 31;
  const int tid = threadIdx.x, lane = tid & 63, w = tid >> 6;
  c[tid] = cum[b * NB_T + tid];
  c[tid + 256] = cum[b * NB_T + tid + 256];
  __syncthreads();
  int ml = c[511]; ml = ml < MAXL ? ml : MAXL;
  const int f0 = chunk * 64 + w * 16;
  for (int i = 0; i < 16; ++i) {
    const int f = f0 + i;
    float o[8] = {0.f, 0.f, 0.f, 0.f, 0.f, 0.f, 0.f, 0.f};
    if (f < ml) {
      int lo = 0, hi = 512;
      while (lo < hi) { int mid = (lo + hi) >> 1; if (c[mid] <= f) lo = mid + 1; else hi = mid; }
      if (lo > 511) lo = 511;
      bf16x8 vv = *(const bf16x8*)(x3b + ((size_t)(b * NB_T + lo)) * 512 + lane * 8);
      #pragma unroll
      for (int j = 0; j < 8; ++j) o[j] = bf2f((ushort_t)vv[j]);
    }
    float* dst = xout + ((size_t)(b * MAXL + f)) * 512 + lane * 8;
    ((float4*)dst)[0] = make_float4(o[0], o[1], o[2], o[3]);
    ((float4*)dst)[1] = make_float4(o[4], o[5], o[6], o[7]);
    if (lane == 0) mmask[b * MAXL + f] = (f >= ml) ? 1.0f : 0.0f;
  }
}

extern "C" void kernel_launch(void* const* d_in, const int* in_sizes, int n_in,
                              void* d_out, int out_size, void* d_ws, size_t ws_size,
                              hipStream_t stream) {
  const float* x        = (const float*)d_in[0];
  const unsigned char* src_mask = (const unsigned char*)d_in[1];
  const int* duration   = (const int*)d_in[2];
  const float* pitch_t  = (const float*)d_in[3];
  const float* energy_t = (const float*)d_in[4];
  const float* conv1_w  = (const float*)d_in[5];
  const float* conv1_b  = (const float*)d_in[6];
  const float* ln1_g    = (const float*)d_in[7];
  const float* ln1_b    = (const float*)d_in[8];
  const float* conv2_w  = (const float*)d_in[9];
  const float* conv2_b  = (const float*)d_in[10];
  const float* ln2_g    = (const float*)d_in[11];
  const float* ln2_b    = (const float*)d_in[12];
  const float* lin_w    = (const float*)d_in[13];
  const float* lin_b    = (const float*)d_in[14];
  const float* pbins    = (const float*)d_in[15];
  const float* ebins    = (const float*)d_in[16];
  const float* ptab     = (const float*)d_in[17];
  const float* etab     = (const float*)d_in[18];

  char* ws = (char*)d_ws;
  ushort_t* wt1    = (ushort_t*)(ws + 0);             //  4,718,592
  ushort_t* wt2    = (ushort_t*)(ws + 4718592);       //  4,718,592
  ushort_t* xb_pad = (ushort_t*)(ws + 9437184);       // 16,842,752  (aliased: lnp0)
  ushort_t* x2pad  = (ushort_t*)(ws + 26279936);      // 16,842,752  (aliased: lnp1)
  ushort_t* lnp2   = (ushort_t*)(ws + 43122688);      // 16,842,752
  ushort_t* hbuf   = (ushort_t*)(ws + 59965440);      // 50,331,648  (3 preds)
  ushort_t* x3b    = (ushort_t*)(ws + 110297088);     // 16,777,216
  int*      cum    = (int*)     (ws + 127074304);     //     65,536

  float* out      = (float*)d_out;
  float* o_xout   = out;                       // 33,554,432
  float* o_preds  = out + 33554432;            // 3 x 16384 (logd, pitch, energy)
  float* o_mellen = o_preds + 3 * NB_M;        // 32
  float* o_mmask  = o_mellen + 32;             // 65,536

  k_cum<<<NB_B, 512, 0, stream>>>(duration, src_mask, cum, o_mellen);
  k_wt<<<dim3(64, 18), 256, 0, stream>>>(conv1_w, conv2_w, wt1, wt2);
  k_prep<<<NB_B * 514, 256, 0, stream>>>(x, pitch_t, energy_t, pbins, ebins, ptab, etab,
                                         xb_pad, x2pad, lnp2, x3b);

  // conv1 for all 3 predictors (pred0,1 read xb_pad; pred2 reads x2pad)
  k_gemm<<<1536, 256, 0, stream>>>(xb_pad, xb_pad, x2pad, wt1, conv1_b, hbuf);
  // LN1 for all 3 (writes padded inputs for conv2; lnp0/lnp1 alias xb_pad/x2pad)
  k_ln_mid<<<3 * NB_M / 4, 256, 0, stream>>>(hbuf, ln1_g, ln1_b, xb_pad, x2pad, lnp2);
  // conv2 for all 3
  k_gemm<<<1536, 256, 0, stream>>>(xb_pad, x2pad, lnp2, wt2, conv2_b, hbuf);
  // LN2 + linear + mask -> all 3 predictions
  k_ln_fin<<<3 * NB_M / 4, 256, 0, stream>>>(hbuf, ln2_g, ln2_b, lin_w, lin_b, src_mask, o_preds);

  k_regulate<<<1024, 256, 0, stream>>>(x3b, cum, o_xout, o_mmask);
}